// Round 12
// baseline (514.231 us; speedup 1.0000x reference)
//
#include <hip/hip_runtime.h>
#include <stdint.h>

// GIN: per layer = dim-sliced gather (slice->XCD affinity, L2-resident) -> z(global)
// -> fused MLP (GEMM1^T -> t(LDS) -> GEMM2 -> coalesced epilogue).
#define NN    20000
#define NE    320000
#define MPAD  20096      // 157 * 128 = 628 * 32
#define DD    256
#define DOUT  128
#define CAP   64
#define NSL   4          // dim slices (64 dims = 128 B each)
#define SLW   64
#define RS    40         // mlp LDS row stride within a 32-K slice
#define SS    2568       // mlp slice stride: 64*40 + 8 pad
#define STS   264        // epilogue u16 staging row stride
#define SFS   132        // epilogue f32 staging row stride

typedef unsigned short u16;
typedef __attribute__((ext_vector_type(8))) __bf16 bf16x8;
typedef __attribute__((ext_vector_type(4))) float  f32x4;

__device__ __forceinline__ uint32_t f2b(float f){
  union { float f; uint32_t u; } x; x.f = f;
  uint32_t r = x.u + 0x7FFFu + ((x.u >> 16) & 1u);   // RNE
  return r >> 16;
}
__device__ __forceinline__ float blo(uint32_t p){ union{uint32_t u;float f;}x; x.u=p<<16;         return x.f; }
__device__ __forceinline__ float bhi(uint32_t p){ union{uint32_t u;float f;}x; x.u=p&0xFFFF0000u; return x.f; }
__device__ __forceinline__ int   fiu(float f){ union{float f;int i;}x; x.f=f; return x.i; }
__device__ __forceinline__ float uif(int i){ union{int i;float f;}x; x.i=i; return x.f; }

// ---------- fused prep: LDS-tiled weight transpose+cast, x->h0 bf16, CSR fill ----------
#define TB 152           // 80 (W1) + 64 (W2a) + 8 (W2l) 64x64 transpose tiles
#define XB (MPAD/4)      // 5024
#define EB ((NE+255)/256)
__global__ __launch_bounds__(256) void prep_all(
    const float* __restrict__ x, const int* __restrict__ src, const int* __restrict__ dst,
    const float* __restrict__ W1, const float* __restrict__ W2a, const float* __restrict__ W2l,
    u16* __restrict__ W1t, u16* __restrict__ W2at, u16* __restrict__ W2lt,
    u16* __restrict__ h0, int* __restrict__ cnt, int* __restrict__ csr)
{
  __shared__ u16 Ts[64][65];
  int b = blockIdx.x, tid = threadIdx.x;
  if (b < TB){
    const float* srcp; u16* dstp; int ldS, k0, n0;
    if (b < 80){
      int layer = b >> 4, sub = b & 15;
      srcp = W1 + layer*65536; dstp = W1t + layer*65536; ldS = 256;
      k0 = (sub >> 2)*64; n0 = (sub & 3)*64;
    } else if (b < 144){
      int bb = b - 80; int layer = bb >> 4, sub = bb & 15;
      srcp = W2a + layer*65536; dstp = W2at + layer*65536; ldS = 256;
      k0 = (sub >> 2)*64; n0 = (sub & 3)*64;
    } else {
      int sub = b - 144;
      srcp = W2l; dstp = W2lt; ldS = 128;
      k0 = (sub >> 1)*64; n0 = (sub & 1)*64;
    }
    int c = tid & 63, r0 = tid >> 6;
    #pragma unroll
    for (int i = 0; i < 16; ++i){
      int r = r0 + i*4;
      Ts[r][c] = (u16)f2b(srcp[(size_t)(k0 + r)*ldS + n0 + c]);
    }
    __syncthreads();
    #pragma unroll
    for (int i = 0; i < 16; ++i){
      int n = r0 + i*4;
      dstp[(size_t)(n0 + n)*256 + k0 + c] = Ts[c][n];
    }
  } else if (b < TB + XB){
    int bb = b - TB;
    int row  = bb*4 + (tid >> 6);
    int lane = tid & 63;
    uint2 o = make_uint2(0u, 0u);
    if (row < NN){
      float4 f = *(const float4*)(x + (size_t)row*DD + lane*4);
      o.x = f2b(f.x) | (f2b(f.y) << 16);
      o.y = f2b(f.z) | (f2b(f.w) << 16);
    }
    *(uint2*)(h0 + (size_t)row*DD + lane*4) = o;
  } else {
    int e = (b - TB - XB)*256 + tid;
    if (e < NE){
      int d = dst[e];
      int slot = atomicAdd(&cnt[d], 1);
      if (slot < CAP) csr[d*CAP + slot] = src[e];
    }
  }
}

// ---------- gather, dim-sliced: block b -> slice b&3, node chunk b>>2 ----------
// Slice s touches only h cols [64s,64s+64) (2.56 MB) -> L2-resident per XCD
// (block->XCD round robin: XCD = b%8 => slice = const per XCD).
// Wave: 32 nodes, processed in pairs; half=lane>>5 edge parity; kl=lane&31 owns 4B.
__global__ __launch_bounds__(256) void gather(
    const u16* __restrict__ hin, const int* __restrict__ cnt, const int* __restrict__ csr,
    const float* __restrict__ eps_arr, int layer, u16* __restrict__ z)
{
  int tid = threadIdx.x, lane = tid & 63, w = tid >> 6;
  int s = blockIdx.x & 3, chunk = blockIdx.x >> 2;
  int half = lane >> 5, kl = lane & 31;
  int xi = (lane ^ 32) << 2;
  float e = 1.0f + eps_arr[layer];
  int v0 = chunk*128 + w*32;                 // wave's 32 nodes (all < MPAD)
  const u16* hs = hin + s*SLW + kl*2;        // lane's 4B within slice
  u16*       zs = z   + s*SLW + kl*2;
  // prefetch all 32 degree counts (contiguous scalar loads)
  int dg[32];
  {
    const int4* cq = (const int4*)(cnt + v0);
    #pragma unroll
    for (int c = 0; c < 8; ++c){
      int4 cc = cq[c];
      dg[4*c+0] = cc.x; dg[4*c+1] = cc.y; dg[4*c+2] = cc.z; dg[4*c+3] = cc.w;
    }
  }
  #pragma unroll 1
  for (int p = 0; p < 16; ++p){
    int va = v0 + 2*p, vb = va + 1;
    int da = dg[2*p];   da = da > CAP ? CAP : da;
    int db = dg[2*p+1]; db = db > CAP ? CAP : db;
    const int4* lqa = (const int4*)(csr + (size_t)va*CAP);
    const int4* lqb = (const int4*)(csr + (size_t)vb*CAP);
    int4 qa[4], qb[4];
    #pragma unroll
    for (int c = 0; c < 4; ++c){ qa[c] = lqa[c]; qb[c] = lqb[c]; }
    float a0=0.f, a1=0.f, b0=0.f, b1=0.f;
    uint32_t ra[8], rb[8];
    int ia[8], ib[8];
    #pragma unroll
    for (int c = 0; c < 4; ++c){
      ia[2*c]   = half ? qa[c].y : qa[c].x;  ia[2*c+1] = half ? qa[c].w : qa[c].z;
      ib[2*c]   = half ? qb[c].y : qb[c].x;  ib[2*c+1] = half ? qb[c].w : qb[c].z;
    }
    #pragma unroll
    for (int c = 0; c < 8; ++c){
      int ga = (2*c + half < da) ? ia[c] : va;
      int gb = (2*c + half < db) ? ib[c] : vb;
      ra[c] = *(const uint32_t*)(hs + (size_t)ga*DD);   // 16 loads in flight
      rb[c] = *(const uint32_t*)(hs + (size_t)gb*DD);
    }
    #pragma unroll
    for (int c = 0; c < 8; ++c){
      if (2*c + half < da){ a0 += blo(ra[c]); a1 += bhi(ra[c]); }
      if (2*c + half < db){ b0 += blo(rb[c]); b1 += bhi(rb[c]); }
    }
    // tails (deg > 16, ~40% of nodes; serial, rare-heavy)
    for (int base = 16; base < da; base += 16){
      int4 q[4];
      #pragma unroll
      for (int c = 0; c < 4; ++c) q[c] = lqa[(base >> 2) + c];
      int id[8];
      #pragma unroll
      for (int c = 0; c < 4; ++c){ id[2*c] = half ? q[c].y : q[c].x; id[2*c+1] = half ? q[c].w : q[c].z; }
      uint32_t rv[8];
      #pragma unroll
      for (int c = 0; c < 8; ++c){
        int g = (base + 2*c + half < da) ? id[c] : va;
        rv[c] = *(const uint32_t*)(hs + (size_t)g*DD);
      }
      #pragma unroll
      for (int c = 0; c < 8; ++c)
        if (base + 2*c + half < da){ a0 += blo(rv[c]); a1 += bhi(rv[c]); }
    }
    for (int base = 16; base < db; base += 16){
      int4 q[4];
      #pragma unroll
      for (int c = 0; c < 4; ++c) q[c] = lqb[(base >> 2) + c];
      int id[8];
      #pragma unroll
      for (int c = 0; c < 4; ++c){ id[2*c] = half ? q[c].y : q[c].x; id[2*c+1] = half ? q[c].w : q[c].z; }
      uint32_t rv[8];
      #pragma unroll
      for (int c = 0; c < 8; ++c){
        int g = (base + 2*c + half < db) ? id[c] : vb;
        rv[c] = *(const uint32_t*)(hs + (size_t)g*DD);
      }
      #pragma unroll
      for (int c = 0; c < 8; ++c)
        if (base + 2*c + half < db){ b0 += blo(rv[c]); b1 += bhi(rv[c]); }
    }
    // own term (half 0 only), cross-half reduce, store
    uint32_t oa = *(const uint32_t*)(hs + (size_t)va*DD);
    uint32_t ob = *(const uint32_t*)(hs + (size_t)vb*DD);
    float ea = (half == 0 && va < NN) ? e : 0.0f;
    float eb = (half == 0 && vb < NN) ? e : 0.0f;
    a0 += ea*blo(oa); a1 += ea*bhi(oa);
    b0 += eb*blo(ob); b1 += eb*bhi(ob);
    a0 += uif(__builtin_amdgcn_ds_bpermute(xi, fiu(a0)));
    a1 += uif(__builtin_amdgcn_ds_bpermute(xi, fiu(a1)));
    b0 += uif(__builtin_amdgcn_ds_bpermute(xi, fiu(b0)));
    b1 += uif(__builtin_amdgcn_ds_bpermute(xi, fiu(b1)));
    if (half == 0){
      *(uint32_t*)(zs + (size_t)va*DD) = f2b(a0) | (f2b(a1) << 16);
      *(uint32_t*)(zs + (size_t)vb*DD) = f2b(b0) | (f2b(b1) << 16);
    }
  }
}

// ---------- fused MLP: GEMM1^T (z from global) -> t(LDS) -> GEMM2 -> epilogue ----------
// M-tile = 64 rows, 314 blocks, 4 waves. (R5-verified kernel.)
__global__ __launch_bounds__(256, 3) void mlp(
    const u16* __restrict__ z,
    const u16* __restrict__ w1, const float* __restrict__ b1,
    const u16* __restrict__ w2, const float* __restrict__ b2,
    const float* __restrict__ gma, const float* __restrict__ bta,
    const float* __restrict__ mu,  const float* __restrict__ var,
    u16* __restrict__ hout, float* __restrict__ outf, int last)
{
  __shared__ __align__(16) u16 As[8*SS];      // t slices; later epilogue staging
  int tid  = threadIdx.x;
  int lane = tid & 63, w = tid >> 6;
  int m0 = blockIdx.x * 64;
  int l15 = lane & 15, l4 = lane >> 4;

  f32x4 acc1[4][4];
  #pragma unroll
  for (int i=0;i<4;++i)
    #pragma unroll
    for (int j=0;j<4;++j){ f32x4 zr={0.f,0.f,0.f,0.f}; acc1[i][j]=zr; }
  {
    int hidb = w*64;
    const u16* zb = z + (size_t)m0*DD;
    for (int s = 0; s < 8; ++s){
      bf16x8 af[4], bz[4];
      #pragma unroll
      for (int mi=0;mi<4;++mi)
        af[mi] = *(const bf16x8*)(w1 + (size_t)(hidb + mi*16 + l15)*DD + s*32 + l4*8);
      #pragma unroll
      for (int nj=0;nj<4;++nj)
        bz[nj] = *(const bf16x8*)(zb + (size_t)(nj*16 + l15)*DD + s*32 + l4*8);
      #pragma unroll
      for (int mi=0;mi<4;++mi)
        #pragma unroll
        for (int nj=0;nj<4;++nj)
          acc1[mi][nj] = __builtin_amdgcn_mfma_f32_16x16x32_bf16(af[mi], bz[nj], acc1[mi][nj], 0,0,0);
    }
  }

  {
    int hidb = w*64;
    #pragma unroll
    for (int mi=0;mi<4;++mi){
      float4 bv = *(const float4*)(b1 + hidb + mi*16 + l4*4);
      int s2 = w*2 + (mi >> 1);
      int kp = (mi & 1)*16 + l4*4;
      #pragma unroll
      for (int nj=0;nj<4;++nj){
        int zrow = nj*16 + l15;
        float v0 = acc1[mi][nj][0] + bv.x; v0 = v0 > 0.f ? v0 : 0.f;
        float v1 = acc1[mi][nj][1] + bv.y; v1 = v1 > 0.f ? v1 : 0.f;
        float v2 = acc1[mi][nj][2] + bv.z; v2 = v2 > 0.f ? v2 : 0.f;
        float v3 = acc1[mi][nj][3] + bv.w; v3 = v3 > 0.f ? v3 : 0.f;
        uint2 pk;
        pk.x = f2b(v0) | (f2b(v1) << 16);
        pk.y = f2b(v2) | (f2b(v3) << 16);
        *(uint2*)(As + s2*SS + zrow*RS + kp) = pk;
      }
    }
  }
  __syncthreads();

  if (!last){
    f32x4 acc2[4][4];
    #pragma unroll
    for (int i=0;i<4;++i)
      #pragma unroll
      for (int j=0;j<4;++j){ f32x4 zr={0.f,0.f,0.f,0.f}; acc2[i][j]=zr; }
    int cb = w*64;
    for (int s = 0; s < 8; ++s){
      bf16x8 at[4], bw[4];
      #pragma unroll
      for (int i=0;i<4;++i)
        at[i] = *(const bf16x8*)(As + s*SS + (i*16 + l15)*RS + l4*8);
      #pragma unroll
      for (int j=0;j<4;++j)
        bw[j] = *(const bf16x8*)(w2 + (size_t)(cb + j*16 + l15)*DD + s*32 + l4*8);
      #pragma unroll
      for (int i=0;i<4;++i)
        #pragma unroll
        for (int j=0;j<4;++j)
          acc2[i][j] = __builtin_amdgcn_mfma_f32_16x16x32_bf16(at[i], bw[j], acc2[i][j], 0,0,0);
    }
    __syncthreads();
    u16* St = As;                          // 64 x 256, stride STS=264
    #pragma unroll
    for (int j=0;j<4;++j){
      int col = cb + j*16 + l15;
      float sc = rsqrtf(var[col] + 1e-5f) * gma[col];
      float sh = (b2[col] - mu[col]) * sc + bta[col];
      #pragma unroll
      for (int i=0;i<4;++i){
        #pragma unroll
        for (int r=0;r<4;++r){
          int row = i*16 + l4*4 + r;
          float vv = acc2[i][j][r]*sc + sh;
          vv = vv > 0.f ? vv : 0.f;
          St[row*STS + col] = (u16)f2b(vv);
        }
      }
    }
    __syncthreads();
    #pragma unroll
    for (int it = 0; it < 8; ++it){
      int idx = it*256 + tid;              // 2048 uint4 = 64 rows x 32 chunks
      int row = idx >> 5, c = idx & 31;
      *(uint4*)(hout + (size_t)(m0 + row)*DD + c*8) = *(const uint4*)(St + row*STS + c*8);
    }
  } else {
    f32x4 acc2[2][4];
    #pragma unroll
    for (int i=0;i<2;++i)
      #pragma unroll
      for (int j=0;j<4;++j){ f32x4 zr={0.f,0.f,0.f,0.f}; acc2[i][j]=zr; }
    int rh = (w >> 1)*32, cbk = (w & 1)*64;
    for (int s = 0; s < 8; ++s){
      bf16x8 at[2], bw[4];
      #pragma unroll
      for (int i=0;i<2;++i)
        at[i] = *(const bf16x8*)(As + s*SS + (rh + i*16 + l15)*RS + l4*8);
      #pragma unroll
      for (int j=0;j<4;++j)
        bw[j] = *(const bf16x8*)(w2 + (size_t)(cbk + j*16 + l15)*DD + s*32 + l4*8);
      #pragma unroll
      for (int i=0;i<2;++i)
        #pragma unroll
        for (int j=0;j<4;++j)
          acc2[i][j] = __builtin_amdgcn_mfma_f32_16x16x32_bf16(at[i], bw[j], acc2[i][j], 0,0,0);
    }
    __syncthreads();
    float* Sf = (float*)As;                // 64 x 128, stride SFS=132
    #pragma unroll
    for (int j=0;j<4;++j){
      int col = cbk + j*16 + l15;
      float sh = b2[col];
      #pragma unroll
      for (int i=0;i<2;++i){
        #pragma unroll
        for (int r=0;r<4;++r){
          int row = rh + i*16 + l4*4 + r;
          Sf[row*SFS + col] = acc2[i][j][r] + sh;
        }
      }
    }
    __syncthreads();
    #pragma unroll
    for (int it = 0; it < 8; ++it){
      int idx = it*256 + tid;              // 2048 uint4 = 64 rows x 32 chunks
      int row = idx >> 5, c = idx & 31;
      if (m0 + row < NN)
        *(uint4*)(outf + (size_t)(m0 + row)*DOUT + c*4) = *(const uint4*)(Sf + row*SFS + c*4);
    }
  }
}

extern "C" void kernel_launch(void* const* d_in, const int* in_sizes, int n_in,
                              void* d_out, int out_size, void* d_ws, size_t ws_size,
                              hipStream_t stream)
{
  const float* x     = (const float*)d_in[0];
  const int*   ei    = (const int*)  d_in[1];
  const float* W1    = (const float*)d_in[2];
  const float* b1    = (const float*)d_in[3];
  const float* W2a   = (const float*)d_in[4];
  const float* b2a   = (const float*)d_in[5];
  const float* W2l   = (const float*)d_in[6];
  const float* b2l   = (const float*)d_in[7];
  const float* eps   = (const float*)d_in[8];
  const float* gma   = (const float*)d_in[9];
  const float* bta   = (const float*)d_in[10];
  const float* mu    = (const float*)d_in[11];
  const float* var   = (const float*)d_in[12];
  float* out = (float*)d_out;

  char* ws = (char*)d_ws;
  size_t off = 0;
  auto alloc = [&](size_t bytes)->void*{
    void* p = ws + off; off += (bytes + 255) & ~(size_t)255; return p;
  };
  u16* h0   = (u16*)alloc((size_t)MPAD*DD*2);
  u16* h1   = (u16*)alloc((size_t)MPAD*DD*2);
  u16* zb   = (u16*)alloc((size_t)MPAD*DD*2);
  int* cnt  = (int*)alloc((size_t)MPAD*4);
  int* csr  = (int*)alloc((size_t)MPAD*CAP*4 + 64);
  u16* W1t  = (u16*)alloc((size_t)5*65536*2);
  u16* W2at = (u16*)alloc((size_t)4*65536*2);
  u16* W2lt = (u16*)alloc((size_t)32768*2);

  const int* srcA = ei;
  const int* dstA = ei + NE;

  hipMemsetAsync(cnt, 0, (size_t)MPAD*4, stream);
  prep_all<<<TB + XB + EB, 256, 0, stream>>>(x, srcA, dstA, W1, W2a, W2l,
                                             W1t, W2at, W2lt, h0, cnt, csr);

  u16* hbuf[2] = { h0, h1 };
  for (int L = 0; L < 5; ++L){
    const u16* hin = hbuf[L & 1];
    u16*       ho  = hbuf[1 - (L & 1)];
    gather<<<NSL*(MPAD/128), 256, 0, stream>>>(hin, cnt, csr, eps, L, zb);
    if (L < 4){
      mlp<<<MPAD/64, 256, 0, stream>>>(zb,
          W1t + (size_t)L*65536, b1 + L*256,
          W2at + (size_t)L*65536, b2a + L*256,
          gma + L*256, bta + L*256, mu + L*256, var + L*256,
          ho, nullptr, 0);
    } else {
      mlp<<<MPAD/64, 256, 0, stream>>>(zb,
          W1t + (size_t)L*65536, b1 + L*256,
          W2lt, b2l,
          nullptr, nullptr, nullptr, nullptr,
          nullptr, out, 1);
    }
  }
}

// Round 13
// 335.224 us; speedup vs baseline: 1.5340x; 1.5340x over previous
//
#include <hip/hip_runtime.h>
#include <stdint.h>

// Fused GIN layer (R10 base): gather with ASM-forced 8-deep load batches ->
// LDS z -> GEMM1^T -> t(LDS) -> GEMM2 -> LDS-staged coalesced epilogue.
// 628 blocks x 4 waves, 32-row tiles.
#define NN    20000
#define NE    320000
#define MPAD  20096      // 628 * 32
#define DD    256
#define DOUT  128
#define CAP   64
#define RS    40         // As row stride (elems) within a 32-K slice
#define SS    1288       // As slice stride: 32*40 + 8 pad
#define STS   264        // epilogue u16 staging row stride
#define SFS   132        // epilogue f32 staging row stride

typedef unsigned short u16;
typedef __attribute__((ext_vector_type(8))) __bf16 bf16x8;
typedef __attribute__((ext_vector_type(4))) float  f32x4;
typedef uint32_t u32x4 __attribute__((ext_vector_type(4)));

__device__ __forceinline__ uint32_t f2b(float f){
  union { float f; uint32_t u; } x; x.f = f;
  uint32_t r = x.u + 0x7FFFu + ((x.u >> 16) & 1u);   // RNE
  return r >> 16;
}
__device__ __forceinline__ float blo(uint32_t p){ union{uint32_t u;float f;}x; x.u=p<<16;         return x.f; }
__device__ __forceinline__ float bhi(uint32_t p){ union{uint32_t u;float f;}x; x.u=p&0xFFFF0000u; return x.f; }
__device__ __forceinline__ int   fiu(float f){ union{float f;int i;}x; x.f=f; return x.i; }
__device__ __forceinline__ float uif(int i){ union{int i;float f;}x; x.i=i; return x.f; }

// 8 independent 16B loads + single drain, opaque to the compiler (cannot be split).
#define GLD8(r0,r1,r2,r3,r4,r5,r6,r7,p0,p1,p2,p3,p4,p5,p6,p7)            \
  asm volatile(                                                          \
    "global_load_dwordx4 %0, %8, off\n\t"                                \
    "global_load_dwordx4 %1, %9, off\n\t"                                \
    "global_load_dwordx4 %2, %10, off\n\t"                               \
    "global_load_dwordx4 %3, %11, off\n\t"                               \
    "global_load_dwordx4 %4, %12, off\n\t"                               \
    "global_load_dwordx4 %5, %13, off\n\t"                               \
    "global_load_dwordx4 %6, %14, off\n\t"                               \
    "global_load_dwordx4 %7, %15, off\n\t"                               \
    "s_waitcnt vmcnt(0)"                                                 \
    : "=&v"(r0), "=&v"(r1), "=&v"(r2), "=&v"(r3),                        \
      "=&v"(r4), "=&v"(r5), "=&v"(r6), "=&v"(r7)                         \
    : "v"(p0), "v"(p1), "v"(p2), "v"(p3),                                \
      "v"(p4), "v"(p5), "v"(p6), "v"(p7)                                 \
    : "memory")

// ---------- fused prep: LDS-tiled weight transpose+cast, x->h0 bf16, CSR fill ----------
#define TB 152           // 80 (W1) + 64 (W2a) + 8 (W2l) 64x64 transpose tiles
#define XB (MPAD/4)      // 5024
#define EB ((NE+255)/256)
__global__ __launch_bounds__(256) void prep_all(
    const float* __restrict__ x, const int* __restrict__ src, const int* __restrict__ dst,
    const float* __restrict__ W1, const float* __restrict__ W2a, const float* __restrict__ W2l,
    u16* __restrict__ W1t, u16* __restrict__ W2at, u16* __restrict__ W2lt,
    u16* __restrict__ h0, int* __restrict__ cnt, int* __restrict__ csr)
{
  __shared__ u16 Ts[64][65];
  int b = blockIdx.x, tid = threadIdx.x;
  if (b < TB){
    const float* srcp; u16* dstp; int ldS, k0, n0;
    if (b < 80){
      int layer = b >> 4, sub = b & 15;
      srcp = W1 + layer*65536; dstp = W1t + layer*65536; ldS = 256;
      k0 = (sub >> 2)*64; n0 = (sub & 3)*64;
    } else if (b < 144){
      int bb = b - 80; int layer = bb >> 4, sub = bb & 15;
      srcp = W2a + layer*65536; dstp = W2at + layer*65536; ldS = 256;
      k0 = (sub >> 2)*64; n0 = (sub & 3)*64;
    } else {
      int sub = b - 144;
      srcp = W2l; dstp = W2lt; ldS = 128;
      k0 = (sub >> 1)*64; n0 = (sub & 1)*64;
    }
    int c = tid & 63, r0 = tid >> 6;
    #pragma unroll
    for (int i = 0; i < 16; ++i){
      int r = r0 + i*4;
      Ts[r][c] = (u16)f2b(srcp[(size_t)(k0 + r)*ldS + n0 + c]);
    }
    __syncthreads();
    #pragma unroll
    for (int i = 0; i < 16; ++i){
      int n = r0 + i*4;
      dstp[(size_t)(n0 + n)*256 + k0 + c] = Ts[c][n];
    }
  } else if (b < TB + XB){
    int bb = b - TB;
    int row  = bb*4 + (tid >> 6);
    int lane = tid & 63;
    uint2 o = make_uint2(0u, 0u);
    if (row < NN){
      float4 f = *(const float4*)(x + (size_t)row*DD + lane*4);
      o.x = f2b(f.x) | (f2b(f.y) << 16);
      o.y = f2b(f.z) | (f2b(f.w) << 16);
    }
    *(uint2*)(h0 + (size_t)row*DD + lane*4) = o;
  } else {
    int e = (b - TB - XB)*256 + tid;
    if (e < NE){
      int d = dst[e];
      int slot = atomicAdd(&cnt[d], 1);
      if (slot < CAP) csr[d*CAP + slot] = src[e];
    }
  }
}

// ---------- fused layer ----------
__global__ __launch_bounds__(256, 3) void gin_fused(
    const u16* __restrict__ hin, const int* __restrict__ cnt, const int* __restrict__ csr,
    const float* __restrict__ eps_arr, int layer,
    const u16* __restrict__ w1, const float* __restrict__ b1,
    const u16* __restrict__ w2, const float* __restrict__ b2,
    const float* __restrict__ gma, const float* __restrict__ bta,
    const float* __restrict__ mu,  const float* __restrict__ var,
    u16* __restrict__ hout, float* __restrict__ outf, int last)
{
  __shared__ __align__(16) u16 As[8*SS];      // z slices -> t slices -> epilogue staging
  int tid  = threadIdx.x;
  int lane = tid & 63, w = tid >> 6;
  int m0 = blockIdx.x * 32;
  int l15 = lane & 15, l4 = lane >> 4;

  // ---- phase 0: gather z = (1+eps)*h[v] + sum_nb h[u] -> As (B-slice layout) ----
  // half=lane>>5 edge parity; kl=lane&31 owns a 16B chunk (8 dims) of the row.
  // Per 16-edge batch: 8 dwordx4 loads forced in flight via GLD8 asm block.
  {
    float e = 1.0f + eps_arr[layer];
    int half = lane >> 5, kl = lane & 31;
    int xi = (lane ^ 32) << 2;                    // bpermute byte index
    const u16* hrow = hin + kl*8;
    u16* dstL = As + (kl >> 2)*SS + (kl & 3)*8;
    for (int i = 0; i < 8; ++i){
      int row = w*8 + i;
      int v = __builtin_amdgcn_readfirstlane(m0 + row);
      float a0=0.f,a1=0.f,a2=0.f,a3=0.f,a4=0.f,a5=0.f,a6=0.f,a7=0.f;
      if (v < NN){
        u32x4 ov = *(const u32x4*)(hrow + (size_t)v*DD);
        int deg = cnt[v]; deg = deg > CAP ? CAP : deg;
        const int4* lq = (const int4*)(csr + (size_t)v*CAP);
        int4 q0 = lq[0], q1 = lq[1], q2 = lq[2], q3 = lq[3];   // batch-0 quads
        for (int base = 0; base < deg; base += 16){
          int idv[8];
          idv[0] = half ? q0.y : q0.x;  idv[1] = half ? q0.w : q0.z;
          idv[2] = half ? q1.y : q1.x;  idv[3] = half ? q1.w : q1.z;
          idv[4] = half ? q2.y : q2.x;  idv[5] = half ? q2.w : q2.z;
          idv[6] = half ? q3.y : q3.x;  idv[7] = half ? q3.w : q3.z;
          const u16* pa[8];
          #pragma unroll
          for (int c = 0; c < 8; ++c){
            int g = (base + 2*c + half < deg) ? idv[c] : v;    // safe addr
            pa[c] = hrow + (size_t)g*DD;
          }
          if (base + 16 < deg){                   // prefetch next batch quads
            q0 = lq[(base >> 2) + 4]; q1 = lq[(base >> 2) + 5];
            q2 = lq[(base >> 2) + 6]; q3 = lq[(base >> 2) + 7];
          }
          u32x4 r0, r1, r2, r3, r4, r5, r6, r7;
          GLD8(r0,r1,r2,r3,r4,r5,r6,r7,
               pa[0],pa[1],pa[2],pa[3],pa[4],pa[5],pa[6],pa[7]);
          u32x4 rv[8] = { r0,r1,r2,r3,r4,r5,r6,r7 };
          #pragma unroll
          for (int c = 0; c < 8; ++c){
            if (base + 2*c + half < deg){
              a0 += blo(rv[c][0]); a1 += bhi(rv[c][0]);
              a2 += blo(rv[c][1]); a3 += bhi(rv[c][1]);
              a4 += blo(rv[c][2]); a5 += bhi(rv[c][2]);
              a6 += blo(rv[c][3]); a7 += bhi(rv[c][3]);
            }
          }
        }
        float eh = half ? 0.0f : e;               // own-term added once (half 0)
        a0 += eh*blo(ov[0]); a1 += eh*bhi(ov[0]);
        a2 += eh*blo(ov[1]); a3 += eh*bhi(ov[1]);
        a4 += eh*blo(ov[2]); a5 += eh*bhi(ov[2]);
        a6 += eh*blo(ov[3]); a7 += eh*bhi(ov[3]);
      }
      // cross-half reduce (register-only permute; all 64 lanes execute)
      a0 += uif(__builtin_amdgcn_ds_bpermute(xi, fiu(a0)));
      a1 += uif(__builtin_amdgcn_ds_bpermute(xi, fiu(a1)));
      a2 += uif(__builtin_amdgcn_ds_bpermute(xi, fiu(a2)));
      a3 += uif(__builtin_amdgcn_ds_bpermute(xi, fiu(a3)));
      a4 += uif(__builtin_amdgcn_ds_bpermute(xi, fiu(a4)));
      a5 += uif(__builtin_amdgcn_ds_bpermute(xi, fiu(a5)));
      a6 += uif(__builtin_amdgcn_ds_bpermute(xi, fiu(a6)));
      a7 += uif(__builtin_amdgcn_ds_bpermute(xi, fiu(a7)));
      if (half == 0){
        u32x4 o;
        o[0] = f2b(a0) | (f2b(a1) << 16);
        o[1] = f2b(a2) | (f2b(a3) << 16);
        o[2] = f2b(a4) | (f2b(a5) << 16);
        o[3] = f2b(a6) | (f2b(a7) << 16);
        *(u32x4*)(dstL + row*RS) = o;
      }
    }
  }
  __syncthreads();

  // ---- phase 1: GEMM1^T: t^T[hid][zrow] = sum_k W1t[hid][k] * z[zrow][k] ----
  f32x4 acc1[4][2];
  #pragma unroll
  for (int i=0;i<4;++i)
    #pragma unroll
    for (int j=0;j<2;++j){ f32x4 zr={0.f,0.f,0.f,0.f}; acc1[i][j]=zr; }
  {
    int hidb = w*64;
    for (int s = 0; s < 8; ++s){
      bf16x8 af[4], bz[2];
      #pragma unroll
      for (int mi=0;mi<4;++mi)
        af[mi] = *(const bf16x8*)(w1 + (size_t)(hidb + mi*16 + l15)*DD + s*32 + l4*8);
      #pragma unroll
      for (int nj=0;nj<2;++nj)
        bz[nj] = *(const bf16x8*)(As + s*SS + (nj*16 + l15)*RS + l4*8);
      #pragma unroll
      for (int mi=0;mi<4;++mi)
        #pragma unroll
        for (int nj=0;nj<2;++nj)
          acc1[mi][nj] = __builtin_amdgcn_mfma_f32_16x16x32_bf16(af[mi], bz[nj], acc1[mi][nj], 0,0,0);
    }
  }
  __syncthreads();   // all z reads done -> reuse As for t

  // ---- phase 2: t = relu(t + b1) -> As in A-operand layout ----
  {
    int hidb = w*64;
    #pragma unroll
    for (int mi=0;mi<4;++mi){
      float4 bv = *(const float4*)(b1 + hidb + mi*16 + l4*4);
      int s2 = w*2 + (mi >> 1);
      int kp = (mi & 1)*16 + l4*4;
      #pragma unroll
      for (int nj=0;nj<2;++nj){
        int zrow = nj*16 + l15;
        float v0 = acc1[mi][nj][0] + bv.x; v0 = v0 > 0.f ? v0 : 0.f;
        float v1 = acc1[mi][nj][1] + bv.y; v1 = v1 > 0.f ? v1 : 0.f;
        float v2 = acc1[mi][nj][2] + bv.z; v2 = v2 > 0.f ? v2 : 0.f;
        float v3 = acc1[mi][nj][3] + bv.w; v3 = v3 > 0.f ? v3 : 0.f;
        uint2 pk;
        pk.x = f2b(v0) | (f2b(v1) << 16);
        pk.y = f2b(v2) | (f2b(v3) << 16);
        *(uint2*)(As + s2*SS + zrow*RS + kp) = pk;
      }
    }
  }
  __syncthreads();

  // ---- phase 3: GEMM2 + epilogue ----
  if (!last){
    f32x4 acc2[2][4];
    #pragma unroll
    for (int i=0;i<2;++i)
      #pragma unroll
      for (int j=0;j<4;++j){ f32x4 zr={0.f,0.f,0.f,0.f}; acc2[i][j]=zr; }
    int cb = w*64;
    for (int s = 0; s < 8; ++s){
      bf16x8 at[2], bw[4];
      #pragma unroll
      for (int i=0;i<2;++i)
        at[i] = *(const bf16x8*)(As + s*SS + (i*16 + l15)*RS + l4*8);
      #pragma unroll
      for (int j=0;j<4;++j)
        bw[j] = *(const bf16x8*)(w2 + (size_t)(cb + j*16 + l15)*DD + s*32 + l4*8);
      #pragma unroll
      for (int i=0;i<2;++i)
        #pragma unroll
        for (int j=0;j<4;++j)
          acc2[i][j] = __builtin_amdgcn_mfma_f32_16x16x32_bf16(at[i], bw[j], acc2[i][j], 0,0,0);
    }
    __syncthreads();                       // done reading t; reuse As for staging
    u16* St = As;                          // 32 x 256, stride STS=264
    #pragma unroll
    for (int j=0;j<4;++j){
      int col = cb + j*16 + l15;
      float sc = rsqrtf(var[col] + 1e-5f) * gma[col];
      float sh = (b2[col] - mu[col]) * sc + bta[col];
      #pragma unroll
      for (int i=0;i<2;++i){
        #pragma unroll
        for (int r=0;r<4;++r){
          int row = i*16 + l4*4 + r;
          float vv = acc2[i][j][r]*sc + sh;
          vv = vv > 0.f ? vv : 0.f;
          St[row*STS + col] = (u16)f2b(vv);
        }
      }
    }
    __syncthreads();
    #pragma unroll
    for (int it = 0; it < 4; ++it){
      int idx = it*256 + tid;              // 1024 uint4 = 32 rows x 32 chunks
      int row = idx >> 5, c = idx & 31;
      *(uint4*)(hout + (size_t)(m0 + row)*DD + c*8) = *(const uint4*)(St + row*STS + c*8);
    }
  } else {
    f32x4 acc2[2][2];
    #pragma unroll
    for (int i=0;i<2;++i)
      #pragma unroll
      for (int j=0;j<2;++j){ f32x4 zr={0.f,0.f,0.f,0.f}; acc2[i][j]=zr; }
    int cbk = w*32;
    for (int s = 0; s < 8; ++s){
      bf16x8 at[2], bw[2];
      #pragma unroll
      for (int i=0;i<2;++i)
        at[i] = *(const bf16x8*)(As + s*SS + (i*16 + l15)*RS + l4*8);
      #pragma unroll
      for (int j=0;j<2;++j)
        bw[j] = *(const bf16x8*)(w2 + (size_t)(cbk + j*16 + l15)*DD + s*32 + l4*8);
      #pragma unroll
      for (int i=0;i<2;++i)
        #pragma unroll
        for (int j=0;j<2;++j)
          acc2[i][j] = __builtin_amdgcn_mfma_f32_16x16x32_bf16(at[i], bw[j], acc2[i][j], 0,0,0);
    }
    __syncthreads();
    float* Sf = (float*)As;                // 32 x 128, stride SFS=132
    #pragma unroll
    for (int j=0;j<2;++j){
      int col = cbk + j*16 + l15;
      float sh = b2[col];
      #pragma unroll
      for (int i=0;i<2;++i){
        #pragma unroll
        for (int r=0;r<4;++r){
          int row = i*16 + l4*4 + r;
          Sf[row*SFS + col] = acc2[i][j][r] + sh;
        }
      }
    }
    __syncthreads();
    #pragma unroll
    for (int it = 0; it < 4; ++it){
      int idx = it*256 + tid;              // 1024 uint4 = 32 rows x 32 chunks
      int row = idx >> 5, c = idx & 31;
      if (m0 + row < NN)
        *(uint4*)(outf + (size_t)(m0 + row)*DOUT + c*4) = *(const uint4*)(Sf + row*SFS + c*4);
    }
  }
}

extern "C" void kernel_launch(void* const* d_in, const int* in_sizes, int n_in,
                              void* d_out, int out_size, void* d_ws, size_t ws_size,
                              hipStream_t stream)
{
  const float* x     = (const float*)d_in[0];
  const int*   ei    = (const int*)  d_in[1];
  const float* W1    = (const float*)d_in[2];
  const float* b1    = (const float*)d_in[3];
  const float* W2a   = (const float*)d_in[4];
  const float* b2a   = (const float*)d_in[5];
  const float* W2l   = (const float*)d_in[6];
  const float* b2l   = (const float*)d_in[7];
  const float* eps   = (const float*)d_in[8];
  const float* gma   = (const float*)d_in[9];
  const float* bta   = (const float*)d_in[10];
  const float* mu    = (const float*)d_in[11];
  const float* var   = (const float*)d_in[12];
  float* out = (float*)d_out;

  char* ws = (char*)d_ws;
  size_t off = 0;
  auto alloc = [&](size_t bytes)->void*{
    void* p = ws + off; off += (bytes + 255) & ~(size_t)255; return p;
  };
  u16* h0   = (u16*)alloc((size_t)MPAD*DD*2);
  u16* h1   = (u16*)alloc((size_t)MPAD*DD*2);
  int* cnt  = (int*)alloc((size_t)MPAD*4);
  int* csr  = (int*)alloc((size_t)MPAD*CAP*4 + 64);
  u16* W1t  = (u16*)alloc((size_t)5*65536*2);
  u16* W2at = (u16*)alloc((size_t)4*65536*2);
  u16* W2lt = (u16*)alloc((size_t)32768*2);

  const int* srcA = ei;
  const int* dstA = ei + NE;

  hipMemsetAsync(cnt, 0, (size_t)MPAD*4, stream);
  prep_all<<<TB + XB + EB, 256, 0, stream>>>(x, srcA, dstA, W1, W2a, W2l,
                                             W1t, W2at, W2lt, h0, cnt, csr);

  u16* hbuf[2] = { h0, h1 };
  for (int L = 0; L < 5; ++L){
    const u16* hin = hbuf[L & 1];
    u16*       ho  = hbuf[1 - (L & 1)];
    if (L < 4){
      gin_fused<<<MPAD/32, 256, 0, stream>>>(hin, cnt, csr, eps, L,
          W1t + (size_t)L*65536, b1 + L*256,
          W2at + (size_t)L*65536, b2a + L*256,
          gma + L*256, bta + L*256, mu + L*256, var + L*256,
          ho, nullptr, 0);
    } else {
      gin_fused<<<MPAD/32, 256, 0, stream>>>(hin, cnt, csr, eps, L,
          W1t + (size_t)L*65536, b1 + L*256,
          W2lt, b2l,
          nullptr, nullptr, nullptr, nullptr,
          nullptr, out, 1);
    }
  }
}